// Round 15
// baseline (1066.670 us; speedup 1.0000x reference)
//
#include <hip/hip_runtime.h>
#include <hip/hip_bf16.h>
#include <math.h>

// Problem constants
#define HID       300
#define HP        320
#define NH        4
#define E_BONDS   60000
#define NATOMS    30000
#define KNB       6
#define NMOLS     600
#define APM       50
#define AFD       144
#define BONDIN    158

typedef unsigned short u16;
typedef unsigned int   u32;
typedef _Float16 f16;
typedef f16   f16x8 __attribute__((ext_vector_type(8)));
typedef float f32x4 __attribute__((ext_vector_type(4)));

// ---------------- helpers ----------------
__device__ inline float hlo(u32 u) { union { u32 i; f16 h[2]; } c; c.i = u; return (float)c.h[0]; }
__device__ inline float hhi(u32 u) { union { u32 i; f16 h[2]; } c; c.i = u; return (float)c.h[1]; }
__device__ inline u32 packh2(float a, float b) {
    union { u32 i; f16 h[2]; } c; c.h[0] = (f16)a; c.h[1] = (f16)b; return c.i;
}

__device__ inline void gl2lds16(const void* g, void* l) {
    __builtin_amdgcn_global_load_lds(
        (const __attribute__((address_space(1))) void*)g,
        (__attribute__((address_space(3))) void*)l, 16, 0, 0);
}

// ---------------------------------------------------------------------------
// MFMA GEMM (round-13 proven: BN=128, 4 waves, launch_bounds(256,4) => 124
// total regs/wave, 16 waves/CU; XCD-aware swizzle).
// 1D grid; linear block b -> xcd=b&7, q=b>>3, xb=q%nbx, yb=(q/nbx)*8+xcd.
// EPI: 0 Cf=v | 1 Ch=h(v) | 2 Ch=h(v),out2=h(relu v) | 3 v+=resid,relu,Ch
//      4 v+=Cf+bias,relu,Cf&Ch | 5 v+=bias,relu,Cf | 6 v+=bias,relu,Ch
// ---------------------------------------------------------------------------
template <int BN, int EPI>
__global__ __launch_bounds__(256, 4) void mfma_gemm_k(
    const f16* __restrict__ A, int lda,
    const f16* __restrict__ B, int ldb,
    int M, int Nb, int K, int ldc,
    int nbx, int mby,
    float* __restrict__ Cf, f16* __restrict__ Ch,
    const float* __restrict__ bias,
    const f16* __restrict__ resid,
    f16* __restrict__ out2)
{
    constexpr int NF = BN / 32;
    __shared__ f16 sA[128 * 64];
    __shared__ f16 sB[BN * 64];
    const int b    = blockIdx.x;
    const int xcd  = b & 7;
    const int q    = b >> 3;
    const int xb   = q % nbx;
    const int yb   = (q / nbx) * 8 + xcd;
    if (yb >= mby) return;
    const int tid  = threadIdx.x;
    const int lane = tid & 63;
    const int wv   = tid >> 6;
    const int wm   = wv >> 1, wn = wv & 1;
    const int m0   = yb * 128, n0 = xb * BN;

    f32x4 acc[4][NF];
#pragma unroll
    for (int i = 0; i < 4; ++i)
#pragma unroll
        for (int j = 0; j < NF; ++j) acc[i][j] = (f32x4){0.f, 0.f, 0.f, 0.f};

    for (int k0 = 0; k0 < K; k0 += 64) {
        __syncthreads();
#pragma unroll
        for (int i = 0; i < 4; ++i) {
            int o   = (((i * 4 + wv) * 64) + lane) * 16;
            int row = o >> 7;
            int p   = (o >> 4) & 7;
            int gr  = m0 + row; gr = gr < M ? gr : M - 1;
            const f16* g = A + (size_t)gr * lda + k0 + ((p ^ (row & 7)) << 3);
            gl2lds16(g, (char*)sA + (i * 4 + wv) * 1024);
        }
#pragma unroll
        for (int i = 0; i < BN / 32; ++i) {
            int o   = (((i * 4 + wv) * 64) + lane) * 16;
            int row = o >> 7;
            int p   = (o >> 4) & 7;
            int gr  = n0 + row; gr = gr < Nb ? gr : Nb - 1;
            const f16* g = B + (size_t)gr * ldb + k0 + ((p ^ (row & 7)) << 3);
            gl2lds16(g, (char*)sB + (i * 4 + wv) * 1024);
        }
        __syncthreads();

        const int rl = lane & 15, cl = lane >> 4;
#pragma unroll
        for (int kh = 0; kh < 2; ++kh) {
            f16x8 af[4], bfr[NF];
#pragma unroll
            for (int mf = 0; mf < 4; ++mf) {
                int row = wm * 64 + mf * 16 + rl;
                int ch  = (kh * 4 + cl) ^ (row & 7);
                af[mf]  = *(const f16x8*)&sA[row * 64 + ch * 8];
            }
#pragma unroll
            for (int nf = 0; nf < NF; ++nf) {
                int row = wn * (BN / 2) + nf * 16 + rl;
                int ch  = (kh * 4 + cl) ^ (row & 7);
                bfr[nf] = *(const f16x8*)&sB[row * 64 + ch * 8];
            }
#pragma unroll
            for (int mf = 0; mf < 4; ++mf)
#pragma unroll
                for (int nf = 0; nf < NF; ++nf)
                    acc[mf][nf] = __builtin_amdgcn_mfma_f32_16x16x32_f16(
                        af[mf], bfr[nf], acc[mf][nf], 0, 0, 0);
        }
    }

    const int rl = lane & 15, cl = lane >> 4;
#pragma unroll
    for (int mf = 0; mf < 4; ++mf) {
#pragma unroll
        for (int r = 0; r < 4; ++r) {
            int gm = m0 + wm * 64 + mf * 16 + cl * 4 + r;
            if (gm >= M) continue;
#pragma unroll
            for (int nf = 0; nf < NF; ++nf) {
                int gn = n0 + wn * (BN / 2) + nf * 16 + rl;
                if (gn >= ldc) continue;
                float v = acc[mf][nf][r];
                size_t ci = (size_t)gm * ldc + gn;
                if (EPI == 0) {
                    Cf[ci] = v;
                } else if (EPI == 1) {
                    Ch[ci] = (f16)v;
                } else if (EPI == 2) {
                    Ch[ci] = (f16)v;
                    out2[ci] = (f16)fmaxf(v, 0.f);
                } else if (EPI == 3) {
                    v += (float)resid[ci];
                    Ch[ci] = (f16)fmaxf(v, 0.f);
                } else if (EPI == 4) {
                    v += Cf[ci];
                    v += (gn < HID) ? bias[gn] : 0.f;
                    v = fmaxf(v, 0.f);
                    Cf[ci] = v; Ch[ci] = (f16)v;
                } else if (EPI == 5) {
                    v += (gn < HID) ? bias[gn] : 0.f;
                    Cf[ci] = fmaxf(v, 0.f);
                } else {                      // EPI == 6
                    v += (gn < HID) ? bias[gn] : 0.f;
                    Ch[ci] = (f16)fmaxf(v, 0.f);
                }
            }
        }
    }
}

// grid size helper (host)
static inline int swz_grid(int nbx, int mby) { return nbx * 8 * ((mby + 7) / 8); }

// ---------------------------------------------------------------------------
// Fused score/softmax/comp, all 4 heads. v2: each 16-thread group owns TWO
// bonds (nei[2][6][10] = 120 VGPR, no MFMA accum pressure -> fits 256-budget,
// launch_bounds(256,2)). Doubles outstanding gathers per thread to probe the
// latency-bound regime of the random 640B nei reads (L3-resident data).
// 32 bonds/block.
// ---------------------------------------------------------------------------
__global__ __launch_bounds__(256, 2) void score_comp_k(
    const f16* __restrict__ msg,     // [E][320] f16
    f16* __restrict__ mtc,           // [E][1280] f16: in mt, out comp
    const int* __restrict__ bgraph)
{
    const int tid = threadIdx.x;
    const int g   = tid >> 4;        // group 0..15
    const int t   = tid & 15;
    const int eA  = blockIdx.x * 32 + g;
    const int eB  = eA + 16;

    u32 nei[2][KNB][10];
#pragma unroll
    for (int p = 0; p < 2; ++p) {
        int e = p ? eB : eA;
#pragma unroll
        for (int k = 0; k < KNB; ++k) {
            int nb = bgraph[e * KNB + k];
            const u32* src = (const u32*)(msg + (size_t)nb * HP) + t * 10;
#pragma unroll
            for (int j = 0; j < 10; ++j) nei[p][k][j] = src[j];
        }
    }

    for (int n = 0; n < NH; ++n) {
#pragma unroll
        for (int p = 0; p < 2; ++p) {
            int e = p ? eB : eA;
            u32* mrow = (u32*)(mtc + (size_t)e * (NH * HP) + n * HP) + t * 10;
            u32 mt[10];
#pragma unroll
            for (int j = 0; j < 10; ++j) mt[j] = mrow[j];

            float pk[KNB] = {0.f, 0.f, 0.f, 0.f, 0.f, 0.f};
#pragma unroll
            for (int j = 0; j < 10; ++j) {
                float m0 = hlo(mt[j]), m1 = hhi(mt[j]);
#pragma unroll
                for (int k = 0; k < KNB; ++k)
                    pk[k] += hlo(nei[p][k][j]) * m0 + hhi(nei[p][k][j]) * m1;
            }
#pragma unroll
            for (int s = 1; s < 16; s <<= 1)
#pragma unroll
                for (int k = 0; k < KNB; ++k) pk[k] += __shfl_xor(pk[k], s);

            float mx = pk[0];
#pragma unroll
            for (int k = 1; k < KNB; ++k) mx = fmaxf(mx, pk[k]);
            float w[KNB], sum = 0.f;
#pragma unroll
            for (int k = 0; k < KNB; ++k) { w[k] = __expf(pk[k] - mx); sum += w[k]; }
            float inv = 1.f / sum;
#pragma unroll
            for (int k = 0; k < KNB; ++k) w[k] *= inv;

#pragma unroll
            for (int j = 0; j < 10; ++j) {
                float c0 = 0.f, c1 = 0.f;
#pragma unroll
                for (int k = 0; k < KNB; ++k) {
                    c0 += w[k] * hlo(nei[p][k][j]);
                    c1 += w[k] * hhi(nei[p][k][j]);
                }
                mrow[j] = packh2(c0, c1);
            }
        }
    }
}

// ---------------------------------------------------------------------------
// Mega-prep: ALL weight preps + fbonds conversion in ONE launch.
// Segments (in order): WiT, WmaT, WhT, Wo512, Wa, Wb, fbondsh.
// ---------------------------------------------------------------------------
#define S_WIT   (320 * 192)
#define S_WMAT  (1280 * 320)
#define S_WHT   (320 * 1280)
#define S_WO    (320 * 512)
#define S_WAB   (320 * 320)
#define S_FB    (E_BONDS * 192)
#define PREP_TOTAL (S_WIT + S_WMAT + S_WHT + S_WO + 2 * S_WAB + S_FB)

__global__ void prep_all_k(
    const float* __restrict__ W_i, const float* __restrict__ W_ma,
    const float* __restrict__ W_h, const float* __restrict__ W_o,
    const float* __restrict__ W_a, const float* __restrict__ W_b,
    const float* __restrict__ fbonds,
    f16* __restrict__ WiT, f16* __restrict__ WmaT, f16* __restrict__ WhT,
    f16* __restrict__ Wo512, f16* __restrict__ Wa, f16* __restrict__ Wb,
    f16* __restrict__ fbondsh)
{
    int idx = blockIdx.x * 256 + threadIdx.x;
    if (idx < S_WIT) {                              // WiT[320][192]
        int r = idx / 192, c = idx - r * 192;
        WiT[idx] = (f16)((r < HID && c < BONDIN) ? W_i[r * BONDIN + c] : 0.f);
        return;
    }
    idx -= S_WIT;
    if (idx < S_WMAT) {                             // WmaT[1280][320]
        int r = idx / 320, c = idx - r * 320;
        int n = r / HP, d = r - n * HP;
        float v = (d < HID && c < HID) ? W_ma[((size_t)n * HID + c) * HID + d] : 0.f;
        WmaT[idx] = (f16)v;
        return;
    }
    idx -= S_WMAT;
    if (idx < S_WHT) {                              // WhT[320][1280]
        int r = idx / 1280, c = idx - r * 1280;
        int n = c / HP, d = c - n * HP;
        float v = (r < HID && d < HID) ? W_h[(size_t)r * (NH * HID) + n * HID + d] : 0.f;
        WhT[idx] = (f16)v;
        return;
    }
    idx -= S_WHT;
    if (idx < S_WO) {                               // Wo512[320][512]
        int r = idx / 512, c = idx - r * 512;
        float v = 0.f;
        if (r < HID) {
            if (c < AFD) v = W_o[r * (AFD + HID) + c];
            else if (c >= 192 && c < 192 + HID) v = W_o[r * (AFD + HID) + AFD + (c - 192)];
        }
        Wo512[idx] = (f16)v;
        return;
    }
    idx -= S_WO;
    if (idx < S_WAB) {                              // Wa[320][320]
        int r = idx / 320, c = idx - r * 320;
        Wa[idx] = (f16)((r < HID && c < HID) ? W_a[r * HID + c] : 0.f);
        return;
    }
    idx -= S_WAB;
    if (idx < S_WAB) {                              // Wb[320][320]
        int r = idx / 320, c = idx - r * 320;
        Wb[idx] = (f16)((r < HID && c < HID) ? W_b[r * HID + c] : 0.f);
        return;
    }
    idx -= S_WAB;
    if (idx < S_FB) {                               // fbondsh[60000][192]
        int r = idx / 192, c = idx - r * 192;
        fbondsh[idx] = (f16)(c < BONDIN ? fbonds[(size_t)r * BONDIN + c] : 0.f);
        return;
    }
}

// ---------------------------------------------------------------------------
// Atom prep: gather-sum a_nei into fat512 cols [192,512) AND convert fatoms
// into cols [0,192), one launch. Segment A: NATOMS*160 u32 pairs; B: f16 conv.
// ---------------------------------------------------------------------------
__global__ void atom_prep_k(const f16* __restrict__ msg,
                            const int* __restrict__ agraph,
                            const float* __restrict__ fatoms,
                            f16* __restrict__ fat512)
{
    int idx = blockIdx.x * 256 + threadIdx.x;
    const int SA = NATOMS * (HP / 2);
    if (idx < SA) {
        int a = idx / (HP / 2), c = idx - a * (HP / 2);
        const int* g = agraph + (size_t)a * KNB;
        float s0 = 0.f, s1 = 0.f;
#pragma unroll
        for (int k = 0; k < KNB; ++k) {
            u32 u = *(const u32*)(msg + (size_t)g[k] * HP + c * 2);
            s0 += hlo(u); s1 += hhi(u);
        }
        ((u32*)fat512)[(size_t)a * 256 + 96 + c] = packh2(s0, s1);
        return;
    }
    idx -= SA;
    if (idx < NATOMS * 192) {
        int r = idx / 192, c = idx - r * 192;
        fat512[(size_t)r * 512 + c] = (f16)(c < AFD ? fatoms[(size_t)r * AFD + c] : 0.f);
    }
}

// ---------------------------------------------------------------------------
// MFMA molecule attention (proven round 4).
// ---------------------------------------------------------------------------
__global__ __launch_bounds__(256) void mol_attn_mfma_k(
    const f16* __restrict__ atomHh,
    const f16* __restrict__ ah2h,
    f16* __restrict__ comp2h)
{
    __shared__ f16 sCur[64 * 320];
    __shared__ float sP[64][66];
    const int tid  = threadIdx.x;
    const int lane = tid & 63;
    const int wv   = tid >> 6;
    const int m    = blockIdx.x;
    const int rl   = lane & 15, cl = lane >> 4;

#pragma unroll
    for (int i = 0; i < 10; ++i) {
        int g   = i * 256 + wv * 64 + lane;
        int row = g / 40, c = g - row * 40;
        int grow = m * APM + row; grow = grow < NATOMS ? grow : NATOMS - 1;
        const f16* src = atomHh + (size_t)grow * HP + ((c ^ (row & 7)) << 3);
        gl2lds16(src, (char*)sCur + (size_t)(i * 256 + wv * 64) * 16);
    }
    __syncthreads();

    f32x4 acc[4];
#pragma unroll
    for (int nf = 0; nf < 4; ++nf) acc[nf] = (f32x4){0.f, 0.f, 0.f, 0.f};
    int qrow = m * APM + wv * 16 + rl;
    qrow = qrow < NATOMS ? qrow : NATOMS - 1;
    const f16* qbase = ah2h + (size_t)qrow * HP;
#pragma unroll
    for (int kh = 0; kh < 10; ++kh) {
        f16x8 aq = *(const f16x8*)(qbase + kh * 32 + cl * 8);
#pragma unroll
        for (int nf = 0; nf < 4; ++nf) {
            int brow = nf * 16 + rl;
            int ch   = (kh * 4 + cl) ^ (brow & 7);
            f16x8 bv = *(const f16x8*)&sCur[brow * 320 + ch * 8];
            acc[nf] = __builtin_amdgcn_mfma_f32_16x16x32_f16(aq, bv, acc[nf], 0, 0, 0);
        }
    }

#pragma unroll
    for (int r = 0; r < 4; ++r) {
        float s[4];
#pragma unroll
        for (int nf = 0; nf < 4; ++nf) {
            s[nf] = acc[nf][r];
            if (nf == 3 && rl >= 2) s[nf] = -1e30f;
        }
        float mx = fmaxf(fmaxf(s[0], s[1]), fmaxf(s[2], s[3]));
#pragma unroll
        for (int msk = 1; msk < 16; msk <<= 1) mx = fmaxf(mx, __shfl_xor(mx, msk));
        float e[4], sum = 0.f;
#pragma unroll
        for (int nf = 0; nf < 4; ++nf) { e[nf] = __expf(s[nf] - mx); sum += e[nf]; }
#pragma unroll
        for (int msk = 1; msk < 16; msk <<= 1) sum += __shfl_xor(sum, msk);
        float inv = 1.f / sum;
        int a = wv * 16 + cl * 4 + r;
#pragma unroll
        for (int nf = 0; nf < 4; ++nf) sP[a][nf * 16 + rl] = e[nf] * inv;
    }
    __syncthreads();

    const int a  = tid >> 2, hq = tid & 3;
    const bool aval = a < APM;
    const size_t orow = (size_t)(m * APM + a) * HP;
#pragma unroll
    for (int p = 0; p < 2; ++p) {
        float av[40];
#pragma unroll
        for (int i = 0; i < 40; ++i) av[i] = 0.f;
        const int ch0 = p * 20 + hq * 5;
        for (int b = 0; b < APM; ++b) {
            float w = sP[a][b];
#pragma unroll
            for (int i = 0; i < 5; ++i) {
                int ch = (ch0 + i) ^ (b & 7);
                f16x8 cv = *(const f16x8*)&sCur[b * 320 + ch * 8];
#pragma unroll
                for (int j = 0; j < 8; ++j) av[i * 8 + j] += w * (float)cv[j];
            }
        }
        if (aval) {
#pragma unroll
            for (int i = 0; i < 5; ++i) {
                f16x8 o;
#pragma unroll
                for (int j = 0; j < 8; ++j) o[j] = (f16)av[i * 8 + j];
                *(f16x8*)&comp2h[orow + p * 160 + hq * 40 + i * 8] = o;
            }
        }
    }
}

// ---------------------------------------------------------------------------
// mol_vecs[m][h] = sum_a (atomHh + atthh)[m*APM+a][h] / APM   (f16 inputs)
// ---------------------------------------------------------------------------
__global__ void mol_reduce_k(const f16* __restrict__ atomHh,
                             const f16* __restrict__ atthh,
                             float* __restrict__ out) {
    const int m = blockIdx.x;
    for (int h = threadIdx.x; h < HID; h += 256) {
        float s = 0.f;
        for (int a = 0; a < APM; ++a) {
            size_t i = (size_t)(m * APM + a) * HP + h;
            s += (float)atomHh[i] + (float)atthh[i];
        }
        out[(size_t)m * HID + h] = s * (1.f / APM);
    }
}

// ---------------------------------------------------------------------------
extern "C" void kernel_launch(void* const* d_in, const int* in_sizes, int n_in,
                              void* d_out, int out_size, void* d_ws, size_t ws_size,
                              hipStream_t stream) {
    const float* fatoms = (const float*)d_in[0];
    const float* fbonds = (const float*)d_in[1];
    const int*   agraph = (const int*)d_in[2];
    const int*   bgraph = (const int*)d_in[3];
    const float* W_i    = (const float*)d_in[4];
    const float* W_ma   = (const float*)d_in[5];
    const float* W_h    = (const float*)d_in[6];
    const float* W_o    = (const float*)d_in[7];
    const float* b_o    = (const float*)d_in[8];
    const float* W_a    = (const float*)d_in[9];
    const float* W_b    = (const float*)d_in[10];
    const float* b_b    = (const float*)d_in[11];
    float* out = (float*)d_out;

    // ---- workspace layout ----
    char* ws = (char*)d_ws;
    f16* fbondsh = (f16*)ws;                         // [60000][192] (pre-MP)
    f16* mtall   = (f16*)ws;                         // [60000][1280] (MP)
    f16* fat512  = (f16*)ws;                         // [30000][512] (post-MP)
    f16* atomHh  = (f16*)(ws + 115200000);           // [30000][320] f16
    f16* ah2h    = (f16*)(ws + 134400000);           // [30000][320] f16
    f16* comp2h  = (f16*)(ws + 153600000);           // [30000][320] f16
    f16* atthh   = (f16*)(ws + 172800000);           // [30000][320] f16
    f16* binh    = (f16*)(ws + 153600000);           // [60000][320] (MP; dead before comp2h)
    f16* msgh    = (f16*)(ws + 192000000);           // [60000][320]
    char* wb = ws + 230400000;
    f16* WiT   = (f16*)(wb);                         // 122880
    f16* WmaT  = (f16*)(wb + 122880);                // 819200
    f16* WhT   = (f16*)(wb + 942080);                // 819200
    f16* Wo512 = (f16*)(wb + 1761280);               // 327680
    f16* Wa    = (f16*)(wb + 2088960);               // 204800
    f16* Wb    = (f16*)(wb + 2293760);               // 204800

    // ---- ONE mega-prep launch: all weights + fbonds conversion ----
    prep_all_k<<<dim3((PREP_TOTAL + 255) / 256), dim3(256), 0, stream>>>(
        W_i, W_ma, W_h, W_o, W_a, W_b, fbonds,
        WiT, WmaT, WhT, Wo512, Wa, Wb, fbondsh);

    // ---- binput/message0 ----
    mfma_gemm_k<128, 2><<<dim3(swz_grid(3, 469)), dim3(256), 0, stream>>>(
        fbondsh, 192, WiT, 192, E_BONDS, 320, 192, HP, 3, 469,
        nullptr, binh, nullptr, nullptr, msgh);

    // ---- 3 message-passing iterations (split pipeline) ----
    for (int it = 0; it < 3; ++it) {
        mfma_gemm_k<128, 1><<<dim3(swz_grid(10, 469)), dim3(256), 0, stream>>>(
            msgh, HP, WmaT, HP, E_BONDS, NH * HP, HP, NH * HP, 10, 469,
            nullptr, mtall, nullptr, nullptr, nullptr);
        score_comp_k<<<dim3(E_BONDS / 32), dim3(256), 0, stream>>>(msgh, mtall, bgraph);
        mfma_gemm_k<128, 3><<<dim3(swz_grid(3, 469)), dim3(256), 0, stream>>>(
            mtall, NH * HP, WhT, NH * HP, E_BONDS, HP, NH * HP, HP, 3, 469,
            nullptr, msgh, nullptr, binh, nullptr);
    }

    // ---- atom stage: one prep launch + one K=512 GEMM ----
    atom_prep_k<<<dim3((NATOMS * (HP / 2) + NATOMS * 192 + 255) / 256), dim3(256), 0, stream>>>(
        msgh, agraph, fatoms, fat512);
    mfma_gemm_k<128, 6><<<dim3(swz_grid(3, 235)), dim3(256), 0, stream>>>(
        fat512, 512, Wo512, 512, NATOMS, 320, 512, HP, 3, 235,
        nullptr, atomHh, b_o, nullptr, nullptr);

    // ---- molecule attention ----
    mfma_gemm_k<128, 1><<<dim3(swz_grid(3, 235)), dim3(256), 0, stream>>>(
        atomHh, HP, Wa, HP, NATOMS, 320, HP, HP, 3, 235,
        nullptr, ah2h, nullptr, nullptr, nullptr);
    mol_attn_mfma_k<<<dim3(NMOLS), dim3(256), 0, stream>>>(atomHh, ah2h, comp2h);
    mfma_gemm_k<128, 6><<<dim3(swz_grid(3, 235)), dim3(256), 0, stream>>>(
        comp2h, HP, Wb, HP, NATOMS, 320, HP, HP, 3, 235,
        nullptr, atthh, b_b, nullptr, nullptr);
    mol_reduce_k<<<dim3(NMOLS), dim3(256), 0, stream>>>(atomHh, atthh, out);
}

// Round 16
// 911.443 us; speedup vs baseline: 1.1703x; 1.1703x over previous
//
#include <hip/hip_runtime.h>
#include <hip/hip_bf16.h>
#include <math.h>

// Problem constants
#define HID       300
#define HP        320
#define NH        4
#define E_BONDS   60000
#define NATOMS    30000
#define KNB       6
#define NMOLS     600
#define APM       50
#define AFD       144
#define BONDIN    158

typedef unsigned short u16;
typedef unsigned int   u32;
typedef _Float16 f16;
typedef f16   f16x8 __attribute__((ext_vector_type(8)));
typedef float f32x4 __attribute__((ext_vector_type(4)));

// ---------------- helpers ----------------
__device__ inline float hlo(u32 u) { union { u32 i; f16 h[2]; } c; c.i = u; return (float)c.h[0]; }
__device__ inline float hhi(u32 u) { union { u32 i; f16 h[2]; } c; c.i = u; return (float)c.h[1]; }
__device__ inline u32 packh2(float a, float b) {
    union { u32 i; f16 h[2]; } c; c.h[0] = (f16)a; c.h[1] = (f16)b; return c.i;
}

__device__ inline void gl2lds16(const void* g, void* l) {
    __builtin_amdgcn_global_load_lds(
        (const __attribute__((address_space(1))) void*)g,
        (__attribute__((address_space(3))) void*)l, 16, 0, 0);
}

// ---------------------------------------------------------------------------
// MFMA GEMM (round-13 proven: BN=128, 4 waves, launch_bounds(256,4) => 124
// total regs/wave, 16 waves/CU; XCD-aware swizzle).
// 1D grid; linear block b -> xcd=b&7, q=b>>3, xb=q%nbx, yb=(q/nbx)*8+xcd.
// EPI: 0 Cf=v | 1 Ch=h(v) | 2 Ch=h(v),out2=h(relu v) | 3 v+=resid,relu,Ch
//      4 v+=Cf+bias,relu,Cf&Ch | 5 v+=bias,relu,Cf | 6 v+=bias,relu,Ch
// ---------------------------------------------------------------------------
template <int BN, int EPI>
__global__ __launch_bounds__(256, 4) void mfma_gemm_k(
    const f16* __restrict__ A, int lda,
    const f16* __restrict__ B, int ldb,
    int M, int Nb, int K, int ldc,
    int nbx, int mby,
    float* __restrict__ Cf, f16* __restrict__ Ch,
    const float* __restrict__ bias,
    const f16* __restrict__ resid,
    f16* __restrict__ out2)
{
    constexpr int NF = BN / 32;
    __shared__ f16 sA[128 * 64];
    __shared__ f16 sB[BN * 64];
    const int b    = blockIdx.x;
    const int xcd  = b & 7;
    const int q    = b >> 3;
    const int xb   = q % nbx;
    const int yb   = (q / nbx) * 8 + xcd;
    if (yb >= mby) return;
    const int tid  = threadIdx.x;
    const int lane = tid & 63;
    const int wv   = tid >> 6;
    const int wm   = wv >> 1, wn = wv & 1;
    const int m0   = yb * 128, n0 = xb * BN;

    f32x4 acc[4][NF];
#pragma unroll
    for (int i = 0; i < 4; ++i)
#pragma unroll
        for (int j = 0; j < NF; ++j) acc[i][j] = (f32x4){0.f, 0.f, 0.f, 0.f};

    for (int k0 = 0; k0 < K; k0 += 64) {
        __syncthreads();
#pragma unroll
        for (int i = 0; i < 4; ++i) {
            int o   = (((i * 4 + wv) * 64) + lane) * 16;
            int row = o >> 7;
            int p   = (o >> 4) & 7;
            int gr  = m0 + row; gr = gr < M ? gr : M - 1;
            const f16* g = A + (size_t)gr * lda + k0 + ((p ^ (row & 7)) << 3);
            gl2lds16(g, (char*)sA + (i * 4 + wv) * 1024);
        }
#pragma unroll
        for (int i = 0; i < BN / 32; ++i) {
            int o   = (((i * 4 + wv) * 64) + lane) * 16;
            int row = o >> 7;
            int p   = (o >> 4) & 7;
            int gr  = n0 + row; gr = gr < Nb ? gr : Nb - 1;
            const f16* g = B + (size_t)gr * ldb + k0 + ((p ^ (row & 7)) << 3);
            gl2lds16(g, (char*)sB + (i * 4 + wv) * 1024);
        }
        __syncthreads();

        const int rl = lane & 15, cl = lane >> 4;
#pragma unroll
        for (int kh = 0; kh < 2; ++kh) {
            f16x8 af[4], bfr[NF];
#pragma unroll
            for (int mf = 0; mf < 4; ++mf) {
                int row = wm * 64 + mf * 16 + rl;
                int ch  = (kh * 4 + cl) ^ (row & 7);
                af[mf]  = *(const f16x8*)&sA[row * 64 + ch * 8];
            }
#pragma unroll
            for (int nf = 0; nf < NF; ++nf) {
                int row = wn * (BN / 2) + nf * 16 + rl;
                int ch  = (kh * 4 + cl) ^ (row & 7);
                bfr[nf] = *(const f16x8*)&sB[row * 64 + ch * 8];
            }
#pragma unroll
            for (int mf = 0; mf < 4; ++mf)
#pragma unroll
                for (int nf = 0; nf < NF; ++nf)
                    acc[mf][nf] = __builtin_amdgcn_mfma_f32_16x16x32_f16(
                        af[mf], bfr[nf], acc[mf][nf], 0, 0, 0);
        }
    }

    const int rl = lane & 15, cl = lane >> 4;
#pragma unroll
    for (int mf = 0; mf < 4; ++mf) {
#pragma unroll
        for (int r = 0; r < 4; ++r) {
            int gm = m0 + wm * 64 + mf * 16 + cl * 4 + r;
            if (gm >= M) continue;
#pragma unroll
            for (int nf = 0; nf < NF; ++nf) {
                int gn = n0 + wn * (BN / 2) + nf * 16 + rl;
                if (gn >= ldc) continue;
                float v = acc[mf][nf][r];
                size_t ci = (size_t)gm * ldc + gn;
                if (EPI == 0) {
                    Cf[ci] = v;
                } else if (EPI == 1) {
                    Ch[ci] = (f16)v;
                } else if (EPI == 2) {
                    Ch[ci] = (f16)v;
                    out2[ci] = (f16)fmaxf(v, 0.f);
                } else if (EPI == 3) {
                    v += (float)resid[ci];
                    Ch[ci] = (f16)fmaxf(v, 0.f);
                } else if (EPI == 4) {
                    v += Cf[ci];
                    v += (gn < HID) ? bias[gn] : 0.f;
                    v = fmaxf(v, 0.f);
                    Cf[ci] = v; Ch[ci] = (f16)v;
                } else if (EPI == 5) {
                    v += (gn < HID) ? bias[gn] : 0.f;
                    Cf[ci] = fmaxf(v, 0.f);
                } else {                      // EPI == 6
                    v += (gn < HID) ? bias[gn] : 0.f;
                    Ch[ci] = (f16)fmaxf(v, 0.f);
                }
            }
        }
    }
}

// grid size helper (host)
static inline int swz_grid(int nbx, int mby) { return nbx * 8 * ((mby + 7) / 8); }

// ---------------------------------------------------------------------------
// Fused score/softmax/comp, all 4 heads (round-14 proven version: 16 bonds/
// block x 16 threads, nei[6][10]=60 VGPR transient, no launch-bounds clamp —
// TLP covers the random-gather latency; ILP x2 variant regressed in r15).
// ---------------------------------------------------------------------------
__global__ __launch_bounds__(256) void score_comp_k(
    const f16* __restrict__ msg,     // [E][320] f16
    f16* __restrict__ mtc,           // [E][1280] f16: in mt, out comp
    const int* __restrict__ bgraph)
{
    const int tid = threadIdx.x;
    const int e   = blockIdx.x * 16 + (tid >> 4);
    const int t   = tid & 15;

    u32 nei[KNB][10];
#pragma unroll
    for (int k = 0; k < KNB; ++k) {
        int nb = bgraph[e * KNB + k];
        const u32* p = (const u32*)(msg + (size_t)nb * HP) + t * 10;
#pragma unroll
        for (int j = 0; j < 10; ++j) nei[k][j] = p[j];
    }

    for (int n = 0; n < NH; ++n) {
        u32* mrow = (u32*)(mtc + (size_t)e * (NH * HP) + n * HP) + t * 10;
        u32 mt[10];
#pragma unroll
        for (int j = 0; j < 10; ++j) mt[j] = mrow[j];

        float pk[KNB] = {0.f, 0.f, 0.f, 0.f, 0.f, 0.f};
#pragma unroll
        for (int j = 0; j < 10; ++j) {
            float m0 = hlo(mt[j]), m1 = hhi(mt[j]);
#pragma unroll
            for (int k = 0; k < KNB; ++k)
                pk[k] += hlo(nei[k][j]) * m0 + hhi(nei[k][j]) * m1;
        }
#pragma unroll
        for (int s = 1; s < 16; s <<= 1)
#pragma unroll
            for (int k = 0; k < KNB; ++k) pk[k] += __shfl_xor(pk[k], s);

        float mx = pk[0];
#pragma unroll
        for (int k = 1; k < KNB; ++k) mx = fmaxf(mx, pk[k]);
        float w[KNB], sum = 0.f;
#pragma unroll
        for (int k = 0; k < KNB; ++k) { w[k] = __expf(pk[k] - mx); sum += w[k]; }
        float inv = 1.f / sum;
#pragma unroll
        for (int k = 0; k < KNB; ++k) w[k] *= inv;

#pragma unroll
        for (int j = 0; j < 10; ++j) {
            float c0 = 0.f, c1 = 0.f;
#pragma unroll
            for (int k = 0; k < KNB; ++k) {
                c0 += w[k] * hlo(nei[k][j]);
                c1 += w[k] * hhi(nei[k][j]);
            }
            mrow[j] = packh2(c0, c1);
        }
    }
}

// ---------------------------------------------------------------------------
// Mega-prep: ALL weight preps + fbonds conversion in ONE launch.
// Segments (in order): WiT, WmaT, WhT, Wo512, Wa, Wb, fbondsh.
// ---------------------------------------------------------------------------
#define S_WIT   (320 * 192)
#define S_WMAT  (1280 * 320)
#define S_WHT   (320 * 1280)
#define S_WO    (320 * 512)
#define S_WAB   (320 * 320)
#define S_FB    (E_BONDS * 192)
#define PREP_TOTAL (S_WIT + S_WMAT + S_WHT + S_WO + 2 * S_WAB + S_FB)

__global__ void prep_all_k(
    const float* __restrict__ W_i, const float* __restrict__ W_ma,
    const float* __restrict__ W_h, const float* __restrict__ W_o,
    const float* __restrict__ W_a, const float* __restrict__ W_b,
    const float* __restrict__ fbonds,
    f16* __restrict__ WiT, f16* __restrict__ WmaT, f16* __restrict__ WhT,
    f16* __restrict__ Wo512, f16* __restrict__ Wa, f16* __restrict__ Wb,
    f16* __restrict__ fbondsh)
{
    int idx = blockIdx.x * 256 + threadIdx.x;
    if (idx < S_WIT) {                              // WiT[320][192]
        int r = idx / 192, c = idx - r * 192;
        WiT[idx] = (f16)((r < HID && c < BONDIN) ? W_i[r * BONDIN + c] : 0.f);
        return;
    }
    idx -= S_WIT;
    if (idx < S_WMAT) {                             // WmaT[1280][320]
        int r = idx / 320, c = idx - r * 320;
        int n = r / HP, d = r - n * HP;
        float v = (d < HID && c < HID) ? W_ma[((size_t)n * HID + c) * HID + d] : 0.f;
        WmaT[idx] = (f16)v;
        return;
    }
    idx -= S_WMAT;
    if (idx < S_WHT) {                              // WhT[320][1280]
        int r = idx / 1280, c = idx - r * 1280;
        int n = c / HP, d = c - n * HP;
        float v = (r < HID && d < HID) ? W_h[(size_t)r * (NH * HID) + n * HID + d] : 0.f;
        WhT[idx] = (f16)v;
        return;
    }
    idx -= S_WHT;
    if (idx < S_WO) {                               // Wo512[320][512]
        int r = idx / 512, c = idx - r * 512;
        float v = 0.f;
        if (r < HID) {
            if (c < AFD) v = W_o[r * (AFD + HID) + c];
            else if (c >= 192 && c < 192 + HID) v = W_o[r * (AFD + HID) + AFD + (c - 192)];
        }
        Wo512[idx] = (f16)v;
        return;
    }
    idx -= S_WO;
    if (idx < S_WAB) {                              // Wa[320][320]
        int r = idx / 320, c = idx - r * 320;
        Wa[idx] = (f16)((r < HID && c < HID) ? W_a[r * HID + c] : 0.f);
        return;
    }
    idx -= S_WAB;
    if (idx < S_WAB) {                              // Wb[320][320]
        int r = idx / 320, c = idx - r * 320;
        Wb[idx] = (f16)((r < HID && c < HID) ? W_b[r * HID + c] : 0.f);
        return;
    }
    idx -= S_WAB;
    if (idx < S_FB) {                               // fbondsh[60000][192]
        int r = idx / 192, c = idx - r * 192;
        fbondsh[idx] = (f16)(c < BONDIN ? fbonds[(size_t)r * BONDIN + c] : 0.f);
        return;
    }
}

// ---------------------------------------------------------------------------
// Atom prep: gather-sum a_nei into fat512 cols [192,512) AND convert fatoms
// into cols [0,192), one launch.
// ---------------------------------------------------------------------------
__global__ void atom_prep_k(const f16* __restrict__ msg,
                            const int* __restrict__ agraph,
                            const float* __restrict__ fatoms,
                            f16* __restrict__ fat512)
{
    int idx = blockIdx.x * 256 + threadIdx.x;
    const int SA = NATOMS * (HP / 2);
    if (idx < SA) {
        int a = idx / (HP / 2), c = idx - a * (HP / 2);
        const int* g = agraph + (size_t)a * KNB;
        float s0 = 0.f, s1 = 0.f;
#pragma unroll
        for (int k = 0; k < KNB; ++k) {
            u32 u = *(const u32*)(msg + (size_t)g[k] * HP + c * 2);
            s0 += hlo(u); s1 += hhi(u);
        }
        ((u32*)fat512)[(size_t)a * 256 + 96 + c] = packh2(s0, s1);
        return;
    }
    idx -= SA;
    if (idx < NATOMS * 192) {
        int r = idx / 192, c = idx - r * 192;
        fat512[(size_t)r * 512 + c] = (f16)(c < AFD ? fatoms[(size_t)r * AFD + c] : 0.f);
    }
}

// ---------------------------------------------------------------------------
// MFMA molecule attention (proven round 4).
// ---------------------------------------------------------------------------
__global__ __launch_bounds__(256) void mol_attn_mfma_k(
    const f16* __restrict__ atomHh,
    const f16* __restrict__ ah2h,
    f16* __restrict__ comp2h)
{
    __shared__ f16 sCur[64 * 320];
    __shared__ float sP[64][66];
    const int tid  = threadIdx.x;
    const int lane = tid & 63;
    const int wv   = tid >> 6;
    const int m    = blockIdx.x;
    const int rl   = lane & 15, cl = lane >> 4;

#pragma unroll
    for (int i = 0; i < 10; ++i) {
        int g   = i * 256 + wv * 64 + lane;
        int row = g / 40, c = g - row * 40;
        int grow = m * APM + row; grow = grow < NATOMS ? grow : NATOMS - 1;
        const f16* src = atomHh + (size_t)grow * HP + ((c ^ (row & 7)) << 3);
        gl2lds16(src, (char*)sCur + (size_t)(i * 256 + wv * 64) * 16);
    }
    __syncthreads();

    f32x4 acc[4];
#pragma unroll
    for (int nf = 0; nf < 4; ++nf) acc[nf] = (f32x4){0.f, 0.f, 0.f, 0.f};
    int qrow = m * APM + wv * 16 + rl;
    qrow = qrow < NATOMS ? qrow : NATOMS - 1;
    const f16* qbase = ah2h + (size_t)qrow * HP;
#pragma unroll
    for (int kh = 0; kh < 10; ++kh) {
        f16x8 aq = *(const f16x8*)(qbase + kh * 32 + cl * 8);
#pragma unroll
        for (int nf = 0; nf < 4; ++nf) {
            int brow = nf * 16 + rl;
            int ch   = (kh * 4 + cl) ^ (brow & 7);
            f16x8 bv = *(const f16x8*)&sCur[brow * 320 + ch * 8];
            acc[nf] = __builtin_amdgcn_mfma_f32_16x16x32_f16(aq, bv, acc[nf], 0, 0, 0);
        }
    }

#pragma unroll
    for (int r = 0; r < 4; ++r) {
        float s[4];
#pragma unroll
        for (int nf = 0; nf < 4; ++nf) {
            s[nf] = acc[nf][r];
            if (nf == 3 && rl >= 2) s[nf] = -1e30f;
        }
        float mx = fmaxf(fmaxf(s[0], s[1]), fmaxf(s[2], s[3]));
#pragma unroll
        for (int msk = 1; msk < 16; msk <<= 1) mx = fmaxf(mx, __shfl_xor(mx, msk));
        float e[4], sum = 0.f;
#pragma unroll
        for (int nf = 0; nf < 4; ++nf) { e[nf] = __expf(s[nf] - mx); sum += e[nf]; }
#pragma unroll
        for (int msk = 1; msk < 16; msk <<= 1) sum += __shfl_xor(sum, msk);
        float inv = 1.f / sum;
        int a = wv * 16 + cl * 4 + r;
#pragma unroll
        for (int nf = 0; nf < 4; ++nf) sP[a][nf * 16 + rl] = e[nf] * inv;
    }
    __syncthreads();

    const int a  = tid >> 2, hq = tid & 3;
    const bool aval = a < APM;
    const size_t orow = (size_t)(m * APM + a) * HP;
#pragma unroll
    for (int p = 0; p < 2; ++p) {
        float av[40];
#pragma unroll
        for (int i = 0; i < 40; ++i) av[i] = 0.f;
        const int ch0 = p * 20 + hq * 5;
        for (int b = 0; b < APM; ++b) {
            float w = sP[a][b];
#pragma unroll
            for (int i = 0; i < 5; ++i) {
                int ch = (ch0 + i) ^ (b & 7);
                f16x8 cv = *(const f16x8*)&sCur[b * 320 + ch * 8];
#pragma unroll
                for (int j = 0; j < 8; ++j) av[i * 8 + j] += w * (float)cv[j];
            }
        }
        if (aval) {
#pragma unroll
            for (int i = 0; i < 5; ++i) {
                f16x8 o;
#pragma unroll
                for (int j = 0; j < 8; ++j) o[j] = (f16)av[i * 8 + j];
                *(f16x8*)&comp2h[orow + p * 160 + hq * 40 + i * 8] = o;
            }
        }
    }
}

// ---------------------------------------------------------------------------
// mol_vecs[m][h] = sum_a (atomHh + atthh)[m*APM+a][h] / APM   (f16 inputs)
// ---------------------------------------------------------------------------
__global__ void mol_reduce_k(const f16* __restrict__ atomHh,
                             const f16* __restrict__ atthh,
                             float* __restrict__ out) {
    const int m = blockIdx.x;
    for (int h = threadIdx.x; h < HID; h += 256) {
        float s = 0.f;
        for (int a = 0; a < APM; ++a) {
            size_t i = (size_t)(m * APM + a) * HP + h;
            s += (float)atomHh[i] + (float)atthh[i];
        }
        out[(size_t)m * HID + h] = s * (1.f / APM);
    }
}

// ---------------------------------------------------------------------------
extern "C" void kernel_launch(void* const* d_in, const int* in_sizes, int n_in,
                              void* d_out, int out_size, void* d_ws, size_t ws_size,
                              hipStream_t stream) {
    const float* fatoms = (const float*)d_in[0];
    const float* fbonds = (const float*)d_in[1];
    const int*   agraph = (const int*)d_in[2];
    const int*   bgraph = (const int*)d_in[3];
    const float* W_i    = (const float*)d_in[4];
    const float* W_ma   = (const float*)d_in[5];
    const float* W_h    = (const float*)d_in[6];
    const float* W_o    = (const float*)d_in[7];
    const float* b_o    = (const float*)d_in[8];
    const float* W_a    = (const float*)d_in[9];
    const float* W_b    = (const float*)d_in[10];
    const float* b_b    = (const float*)d_in[11];
    float* out = (float*)d_out;

    // ---- workspace layout ----
    char* ws = (char*)d_ws;
    f16* fbondsh = (f16*)ws;                         // [60000][192] (pre-MP)
    f16* mtall   = (f16*)ws;                         // [60000][1280] (MP)
    f16* fat512  = (f16*)ws;                         // [30000][512] (post-MP)
    f16* atomHh  = (f16*)(ws + 115200000);           // [30000][320] f16
    f16* ah2h    = (f16*)(ws + 134400000);           // [30000][320] f16
    f16* comp2h  = (f16*)(ws + 153600000);           // [30000][320] f16
    f16* atthh   = (f16*)(ws + 172800000);           // [30000][320] f16
    f16* binh    = (f16*)(ws + 153600000);           // [60000][320] (MP; dead before comp2h)
    f16* msgh    = (f16*)(ws + 192000000);           // [60000][320]
    char* wb = ws + 230400000;
    f16* WiT   = (f16*)(wb);                         // 122880
    f16* WmaT  = (f16*)(wb + 122880);                // 819200
    f16* WhT   = (f16*)(wb + 942080);                // 819200
    f16* Wo512 = (f16*)(wb + 1761280);               // 327680
    f16* Wa    = (f16*)(wb + 2088960);               // 204800
    f16* Wb    = (f16*)(wb + 2293760);               // 204800

    // ---- ONE mega-prep launch: all weights + fbonds conversion ----
    prep_all_k<<<dim3((PREP_TOTAL + 255) / 256), dim3(256), 0, stream>>>(
        W_i, W_ma, W_h, W_o, W_a, W_b, fbonds,
        WiT, WmaT, WhT, Wo512, Wa, Wb, fbondsh);

    // ---- binput/message0 ----
    mfma_gemm_k<128, 2><<<dim3(swz_grid(3, 469)), dim3(256), 0, stream>>>(
        fbondsh, 192, WiT, 192, E_BONDS, 320, 192, HP, 3, 469,
        nullptr, binh, nullptr, nullptr, msgh);

    // ---- 3 message-passing iterations (split pipeline) ----
    for (int it = 0; it < 3; ++it) {
        mfma_gemm_k<128, 1><<<dim3(swz_grid(10, 469)), dim3(256), 0, stream>>>(
            msgh, HP, WmaT, HP, E_BONDS, NH * HP, HP, NH * HP, 10, 469,
            nullptr, mtall, nullptr, nullptr, nullptr);
        score_comp_k<<<dim3(E_BONDS / 16), dim3(256), 0, stream>>>(msgh, mtall, bgraph);
        mfma_gemm_k<128, 3><<<dim3(swz_grid(3, 469)), dim3(256), 0, stream>>>(
            mtall, NH * HP, WhT, NH * HP, E_BONDS, HP, NH * HP, HP, 3, 469,
            nullptr, msgh, nullptr, binh, nullptr);
    }

    // ---- atom stage: one prep launch + one K=512 GEMM ----
    atom_prep_k<<<dim3((NATOMS * (HP / 2) + NATOMS * 192 + 255) / 256), dim3(256), 0, stream>>>(
        msgh, agraph, fatoms, fat512);
    mfma_gemm_k<128, 6><<<dim3(swz_grid(3, 235)), dim3(256), 0, stream>>>(
        fat512, 512, Wo512, 512, NATOMS, 320, 512, HP, 3, 235,
        nullptr, atomHh, b_o, nullptr, nullptr);

    // ---- molecule attention ----
    mfma_gemm_k<128, 1><<<dim3(swz_grid(3, 235)), dim3(256), 0, stream>>>(
        atomHh, HP, Wa, HP, NATOMS, 320, HP, HP, 3, 235,
        nullptr, ah2h, nullptr, nullptr, nullptr);
    mol_attn_mfma_k<<<dim3(NMOLS), dim3(256), 0, stream>>>(atomHh, ah2h, comp2h);
    mfma_gemm_k<128, 6><<<dim3(swz_grid(3, 235)), dim3(256), 0, stream>>>(
        comp2h, HP, Wb, HP, NATOMS, 320, HP, HP, 3, 235,
        nullptr, atthh, b_b, nullptr, nullptr);
    mol_reduce_k<<<dim3(NMOLS), dim3(256), 0, stream>>>(atomHh, atthh, out);
}